// Round 2
// baseline (1599.993 us; speedup 1.0000x reference)
//
#include <hip/hip_runtime.h>
#include <hip/hip_bf16.h>

#define Bt 16
#define Ct 16
#define Nt 64
#define Dt 32
#define HIDt 64
#define KITERt 4

// ---------- weight fp32 block layout (floats) ----------
// wq 512 | bq 32 | wk 512 | bk 32 | wm 2304 | bm 16 | w1 4096 | b1 64 |
// w2 4096 | b2 64 | wo 64 | bo 1 | gb 16 | wg 9216 | bg 32 | wc 4608 | bc 16
#define WF_TOTAL 25681

__device__ inline float bf2f(__hip_bfloat16 v) { return __bfloat162float(v); }

// Read element i of an external float array whose true dtype is decided at
// runtime: isf32 ? float32 : bfloat16.
__device__ inline float loadf(const void* p, int i, int isf32) {
    return isf32 ? ((const float*)p)[i]
                 : __bfloat162float(((const __hip_bfloat16*)p)[i]);
}

// ---------------- dtype probe: bf16 interpretation of fp32 data explodes ----------------
__global__ void probe_kernel(const void* __restrict__ seed, int* __restrict__ flag)
{
    __shared__ float red[256];
    int t = threadIdx.x;
    const __hip_bfloat16* p = (const __hip_bfloat16*)seed;
    float mx = 0.f;
    for (int k = 0; k < 16; ++k) {
        float v = fabsf(__bfloat162float(p[t * 16 + k]));
        if (!(v <= 1e30f)) v = 1e30f;   // NaN/inf -> huge
        mx = fmaxf(mx, v);
    }
    red[t] = mx;
    __syncthreads();
    if (t == 0) {
        float m = 0.f;
        for (int k = 0; k < 256; ++k) m = fmaxf(m, red[k]);
        *flag = (m > 1e10f) ? 1 : 0;   // 1 => inputs are float32
    }
}

// ---------------- prep: convert weights to fp32, build T, build edge lists ----------------
__global__ void prep_kernel(
    const void* __restrict__ wq, const void* __restrict__ bq,
    const void* __restrict__ wk, const void* __restrict__ bk,
    const void* __restrict__ wm, const void* __restrict__ bm,
    const void* __restrict__ w1, const void* __restrict__ b1,
    const void* __restrict__ w2, const void* __restrict__ b2,
    const void* __restrict__ wo, const void* __restrict__ bo,
    const void* __restrict__ gw, const void* __restrict__ gb,
    const void* __restrict__ wg, const void* __restrict__ bg,
    const void* __restrict__ wc, const void* __restrict__ bc,
    const int* __restrict__ edge, int E,
    float* __restrict__ Wf, float* __restrict__ Tf,
    int* __restrict__ counts, int* __restrict__ lists,
    const int* __restrict__ flagp)
{
    int isf32 = *flagp;
    int idx = blockIdx.x * 256 + threadIdx.x;
    if (idx < WF_TOTAL) {
        int i = idx;
        const void* base;
        if (i < 512) base = wq;
        else if ((i -= 512) < 32) base = bq;
        else if ((i -= 32) < 512) base = wk;
        else if ((i -= 512) < 32) base = bk;
        else if ((i -= 32) < 2304) base = wm;
        else if ((i -= 2304) < 16) base = bm;
        else if ((i -= 16) < 4096) base = w1;
        else if ((i -= 4096) < 64) base = b1;
        else if ((i -= 64) < 4096) base = w2;
        else if ((i -= 4096) < 64) base = b2;
        else if ((i -= 64) < 64) base = wo;
        else if ((i -= 64) < 1) base = bo;
        else if ((i -= 1) < 16) base = gb;
        else if ((i -= 16) < 9216) base = wg;
        else if ((i -= 9216) < 32) base = bg;
        else if ((i -= 32) < 4608) base = wc;
        else { i -= 4608; base = bc; }
        Wf[idx] = loadf(base, i, isf32);
    } else if (idx < WF_TOTAL + 4096) {
        // T[c,y,x] = conv(ones(1,1,16,16), g_w)[c,y,x]
        int i = idx - WF_TOTAL;
        int c = i >> 8, pix = i & 255;
        int y = pix >> 4, x = pix & 15;
        float s = 0.f;
        for (int ky = 0; ky < 3; ++ky)
            for (int kx = 0; kx < 3; ++kx) {
                int yy = y + ky - 1, xx = x + kx - 1;
                if (yy >= 0 && yy < 16 && xx >= 0 && xx < 16)
                    s += loadf(gw, c * 9 + ky * 3 + kx, isf32);
            }
        Tf[i] = s;
    } else if (idx < WF_TOTAL + 4096 + Nt) {
        int i = idx - WF_TOTAL - 4096;  // node id
        int deg = 0;
        for (int e = 0; e < E; ++e)
            if (edge[2 * e] == i) { if (deg < 8) lists[i * 8 + deg] = e; ++deg; }
        counts[i] = deg < 8 ? deg : 8;
    }
}

// ---------------- unpack: seed (B,C,128,128) -> X (B,N,C,16,16) fp32 ----------------
__global__ void unpack_kernel(const void* __restrict__ seed, float* __restrict__ X,
                              const int* __restrict__ flagp)
{
    int isf32 = *flagp;
    int idx = blockIdx.x * 256 + threadIdx.x;  // over X layout
    int pix = idx & 255;
    int rest = idx >> 8;
    int c = rest & 15; rest >>= 4;
    int n = rest & 63; int b = rest >> 6;
    int p = n >> 3, q = n & 7;
    int y = pix >> 4, x = pix & 15;
    X[idx] = loadf(seed, ((b * 16 + c) * 128 + p * 16 + y) * 128 + q * 16 + x, isf32);
}

// ---------------- pack: X fp32 -> out (B,C,128,128) in output dtype ----------------
__global__ void pack_kernel(const float* __restrict__ X, void* __restrict__ out,
                            const int* __restrict__ flagp)
{
    int isf32 = *flagp;
    int idx = blockIdx.x * 256 + threadIdx.x;  // over out layout
    int xx = idx & 127;
    int rest = idx >> 7;
    int yy = rest & 127; rest >>= 7;
    int c = rest & 15; int b = rest >> 4;
    int p = yy >> 4, q = xx >> 4;
    int n = p * 8 + q;
    float v = X[(((b * 64 + n) * 16 + c) << 8) + (yy & 15) * 16 + (xx & 15)];
    if (isf32) ((float*)out)[idx] = v;
    else ((__hip_bfloat16*)out)[idx] = __float2bfloat16(v);
}

// ---------------- per-patch mean + q/k projections ----------------
__global__ __launch_bounds__(256) void stats_qk_kernel(
    const float* __restrict__ X,
    const float* __restrict__ Wq, const float* __restrict__ bqf,
    const float* __restrict__ Wk, const float* __restrict__ bkf,
    float* __restrict__ qv, float* __restrict__ kv)
{
    int bn = blockIdx.x;
    const float* xp = X + bn * Ct * 256;
    __shared__ float red[256];
    __shared__ float xm[16];
    int t = threadIdx.x;
    int c = t >> 4, s = t & 15;
    float acc = 0.f;
#pragma unroll
    for (int k = 0; k < 16; ++k) acc += xp[c * 256 + k * 16 + s];
    red[t] = acc;
    __syncthreads();
    if (t < 16) {
        float m = 0.f;
#pragma unroll
        for (int k = 0; k < 16; ++k) m += red[t * 16 + k];
        xm[t] = m * (1.0f / 256.0f);
    }
    __syncthreads();
    if (t < 32) {
        float a = bqf[t];
#pragma unroll
        for (int c2 = 0; c2 < 16; ++c2) a += xm[c2] * Wq[c2 * 32 + t];
        qv[bn * 32 + t] = a;
    } else if (t < 64) {
        int d = t - 32;
        float a = bkf[d];
#pragma unroll
        for (int c2 = 0; c2 < 16; ++c2) a += xm[c2] * Wk[c2 * 32 + d];
        kv[bn * 32 + d] = a;
    }
}

// ---------------- message conv: M = conv3x3(X, wm) + bm, per patch (bf16 out) ----------------
__global__ __launch_bounds__(256) void conv_m_kernel(
    const float* __restrict__ X, const float* __restrict__ Wm, const float* __restrict__ bmf,
    __hip_bfloat16* __restrict__ M)
{
    int bn = blockIdx.x;
    const float* xp = X + bn * Ct * 256;
    __shared__ float sx[16][324];  // 18x18 zero-padded
    int t = threadIdx.x;
    for (int idx = t; idx < 16 * 324; idx += 256) {
        int cch = idx / 324, p = idx % 324;
        int yy = p / 18 - 1, xx = p % 18 - 1;
        float v = 0.f;
        if (yy >= 0 && yy < 16 && xx >= 0 && xx < 16) v = xp[cch * 256 + yy * 16 + xx];
        sx[cch][p] = v;
    }
    __syncthreads();
    int y = t >> 4, x = t & 15;
    float acc[16];
#pragma unroll
    for (int co = 0; co < 16; ++co) acc[co] = bmf[co];
    for (int ci = 0; ci < 16; ++ci) {
#pragma unroll
        for (int ky = 0; ky < 3; ++ky)
#pragma unroll
            for (int kx = 0; kx < 3; ++kx) {
                float v = sx[ci][(y + ky) * 18 + (x + kx)];
                int wo0 = ci * 9 + ky * 3 + kx;
#pragma unroll
                for (int co = 0; co < 16; ++co) acc[co] += v * Wm[co * 144 + wo0];
            }
    }
    __hip_bfloat16* mp = M + bn * Ct * 256;
#pragma unroll
    for (int co = 0; co < 16; ++co) mp[co * 256 + t] = __float2bfloat16(acc[co]);
}

// ---------------- edge MLP: one wave per (b, edge) ----------------
__global__ __launch_bounds__(256) void edge_mlp_kernel(
    const int* __restrict__ edge, int E,
    const float* __restrict__ qv, const float* __restrict__ kv,
    const float* __restrict__ W1, const float* __restrict__ b1f,
    const float* __restrict__ W2, const float* __restrict__ b2f,
    const float* __restrict__ Wo, const float* __restrict__ bof,
    float* __restrict__ ev)
{
    int wave = (blockIdx.x * 256 + threadIdx.x) >> 6;
    int lane = threadIdx.x & 63;
    if (wave >= Bt * 224) return;
    int b = wave / E, e = wave % E;
    int ei = edge[2 * e], ej = edge[2 * e + 1];
    float h0 = (lane < 32) ? qv[(b * Nt + ei) * 32 + lane]
                           : kv[(b * Nt + ej) * 32 + (lane - 32)];
    float a1 = b1f[lane];
    for (int j = 0; j < 64; ++j) {
        float v = __shfl(h0, j, 64);
        a1 += v * W1[j * 64 + lane];
    }
    a1 = fmaxf(a1, 0.f);
    float a2 = b2f[lane];
    for (int j = 0; j < 64; ++j) {
        float v = __shfl(a1, j, 64);
        a2 += v * W2[j * 64 + lane];
    }
    a2 = fmaxf(a2, 0.f);
    float pe = a2 * Wo[lane];
    for (int off = 32; off; off >>= 1) pe += __shfl_down(pe, off, 64);
    if (lane == 0) ev[wave] = pe + bof[0];
}

// ---------------- fused aggregate + conv-GRU update (per patch, in-place X) ----------------
__global__ __launch_bounds__(256) void gru_kernel(
    float* __restrict__ X, const __hip_bfloat16* __restrict__ M,
    const float* __restrict__ ev, const float* __restrict__ Tf,
    const float* __restrict__ gbf,
    const float* __restrict__ Wg, const float* __restrict__ bgf,
    const float* __restrict__ Wc, const float* __restrict__ bcf,
    const int* __restrict__ edge, const int* __restrict__ counts, const int* __restrict__ lists,
    int E)
{
    int bn = blockIdx.x;
    int b = bn >> 6, i = bn & 63;
    __shared__ float sA[16][324];  // M_agg, 18x18 padded
    __shared__ float sH[16][324];  // h, padded
    __shared__ float sR[16][324];  // r*h, padded
    int t = threadIdx.x;
    for (int idx = t; idx < 16 * 324; idx += 256) {
        int cch = idx / 324, p = idx % 324;
        int yy = p / 18 - 1, xx = p % 18 - 1;
        float hv = 0.f;
        if (yy >= 0 && yy < 16 && xx >= 0 && xx < 16)
            hv = X[bn * Ct * 256 + cch * 256 + yy * 16 + xx];
        sH[cch][p] = hv;
        sA[cch][p] = 0.f;
        sR[cch][p] = 0.f;
    }
    __syncthreads();
    int deg = counts[i];
    for (int ii = 0; ii < deg; ++ii) {
        int e = lists[i * 8 + ii];
        int ej = edge[2 * e + 1];
        float evv = ev[b * E + e];
        const __hip_bfloat16* mp = M + (b * Nt + ej) * Ct * 256;
        for (int idx = t; idx < 4096; idx += 256) {
            int cch = idx >> 8, pix = idx & 255;
            float g = 1.f / (1.f + expf(-(evv * Tf[idx] + gbf[cch])));
            int y = pix >> 4, x = pix & 15;
            sA[cch][(y + 1) * 18 + x + 1] += g * bf2f(mp[idx]);
        }
    }
    __syncthreads();
    int y = t >> 4, x = t & 15;
    float acc[32];
#pragma unroll
    for (int co = 0; co < 32; ++co) acc[co] = bgf[co];
    for (int ci = 0; ci < 32; ++ci) {
        const float* tile = (ci < 16) ? &sA[ci][0] : &sH[ci - 16][0];
#pragma unroll
        for (int ky = 0; ky < 3; ++ky)
#pragma unroll
            for (int kx = 0; kx < 3; ++kx) {
                float v = tile[(y + ky) * 18 + (x + kx)];
                int wo0 = ci * 9 + ky * 3 + kx;
#pragma unroll
                for (int co = 0; co < 32; ++co) acc[co] += v * Wg[co * 288 + wo0];
            }
    }
    float zv[16];
#pragma unroll
    for (int c = 0; c < 16; ++c) {
        zv[c] = 1.f / (1.f + expf(-acc[c]));
        float r = 1.f / (1.f + expf(-acc[16 + c]));
        sR[c][(y + 1) * 18 + x + 1] = r * sH[c][(y + 1) * 18 + x + 1];
    }
    __syncthreads();
    float acc2[16];
#pragma unroll
    for (int co = 0; co < 16; ++co) acc2[co] = bcf[co];
    for (int ci = 0; ci < 32; ++ci) {
        const float* tile = (ci < 16) ? &sA[ci][0] : &sR[ci - 16][0];
#pragma unroll
        for (int ky = 0; ky < 3; ++ky)
#pragma unroll
            for (int kx = 0; kx < 3; ++kx) {
                float v = tile[(y + ky) * 18 + (x + kx)];
                int wo0 = ci * 9 + ky * 3 + kx;
#pragma unroll
                for (int co = 0; co < 16; ++co) acc2[co] += v * Wc[co * 288 + wo0];
            }
    }
#pragma unroll
    for (int co = 0; co < 16; ++co) {
        float cand = tanhf(acc2[co]);
        float h = sH[co][(y + 1) * 18 + x + 1];
        X[bn * Ct * 256 + co * 256 + t] = (1.f - zv[co]) * h + zv[co] * cand;
    }
}

extern "C" void kernel_launch(void* const* d_in, const int* in_sizes, int n_in,
                              void* d_out, int out_size, void* d_ws, size_t ws_size,
                              hipStream_t stream)
{
    const void* seed = d_in[0];
    const int* edge = (const int*)d_in[1];
    const int E = in_sizes[1] / 2;  // 224
    const int XTOT = Bt * Nt * Ct * 256;  // 4,194,304

    float* ws = (float*)d_ws;
    float* Xf = ws;                       // 4,194,304 floats (16 MB)
    float* qv = Xf + XTOT;                // 32768
    float* kv = qv + Bt * Nt * Dt;        // 32768
    float* ev = kv + Bt * Nt * Dt;        // 3584
    float* Tf = ev + Bt * 224;            // 4096
    float* Wf = Tf + 4096;                // 25681
    int* flag = (int*)(Wf + WF_TOTAL);    // 1
    int* counts = flag + 64;              // 64
    int* lists = counts + 64;             // 512

    // M lives in d_out as bf16 scratch (overwritten by pack at the end)
    __hip_bfloat16* Mb = (__hip_bfloat16*)d_out;

    // fp32 weight sub-pointers (must match prep_kernel chain order)
    float* Wqf = Wf;
    float* bqf = Wqf + 512;
    float* Wkf = bqf + 32;
    float* bkf = Wkf + 512;
    float* Wmf = bkf + 32;
    float* bmf = Wmf + 2304;
    float* W1f = bmf + 16;
    float* b1f = W1f + 4096;
    float* W2f = b1f + 64;
    float* b2f = W2f + 4096;
    float* Wof = b2f + 64;
    float* bof = Wof + 64;
    float* gbf = bof + 1;
    float* Wgf = gbf + 16;
    float* bgf = Wgf + 9216;
    float* Wcf = bgf + 32;
    float* bcf = Wcf + 4608;

    probe_kernel<<<1, 256, 0, stream>>>(seed, flag);

    int prep_blocks = (WF_TOTAL + 4096 + Nt + 255) / 256;
    prep_kernel<<<prep_blocks, 256, 0, stream>>>(
        d_in[2], d_in[3], d_in[4], d_in[5], d_in[6], d_in[7], d_in[8], d_in[9],
        d_in[10], d_in[11], d_in[12], d_in[13], d_in[14], d_in[15], d_in[16],
        d_in[17], d_in[18], d_in[19],
        edge, E, Wf, Tf, counts, lists, flag);

    unpack_kernel<<<XTOT / 256, 256, 0, stream>>>(seed, Xf, flag);

    int mlp_blocks = (Bt * E * 64 + 255) / 256;
    for (int it = 0; it < KITERt; ++it) {
        stats_qk_kernel<<<Bt * Nt, 256, 0, stream>>>(Xf, Wqf, bqf, Wkf, bkf, qv, kv);
        conv_m_kernel<<<Bt * Nt, 256, 0, stream>>>(Xf, Wmf, bmf, Mb);
        edge_mlp_kernel<<<mlp_blocks, 256, 0, stream>>>(edge, E, qv, kv, W1f, b1f, W2f, b2f, Wof, bof, ev);
        gru_kernel<<<Bt * Nt, 256, 0, stream>>>(Xf, Mb, ev, Tf, gbf, Wgf, bgf, Wcf, bcf,
                                                edge, counts, lists, E);
    }

    pack_kernel<<<XTOT / 256, 256, 0, stream>>>(Xf, d_out, flag);
}

// Round 3
// 404.676 us; speedup vs baseline: 3.9538x; 3.9538x over previous
//
#include <hip/hip_runtime.h>
#include <hip/hip_bf16.h>

#define Bt 16
#define Ct 16
#define Nt 64
#define Dt 32
#define HIDt 64
#define KITERt 4

// ---------- weight fp32 block layout (floats) ----------
// wq 512 | bq 32 | wk 512 | bk 32 | wm 2304 | bm 16 | w1 4096 | b1 64 |
// w2 4096 | b2 64 | wo 64 | bo 1 | gb 16 | wg 9216 | bg 32 | wc 4608 | bc 16
#define WF_TOTAL 25681
// swizzled bf16 MFMA B-frag blocks: WgS 9216 | WcS 4608 | WmS 2560
#define SWZ_TOTAL 16384

typedef __attribute__((ext_vector_type(8))) short bf16x8;
typedef __attribute__((ext_vector_type(4))) float f32x4;

__device__ inline float bf2f(__hip_bfloat16 v) { return __bfloat162float(v); }
__device__ inline short f2bs(float f) {
    __hip_bfloat16 h = __float2bfloat16(f);
    short s; __builtin_memcpy(&s, &h, 2); return s;
}
__device__ inline float bs2f(short s) {
    __hip_bfloat16 h; __builtin_memcpy(&h, &s, 2);
    return __bfloat162float(h);
}
__device__ inline float loadf(const void* p, int i, int isf32) {
    return isf32 ? ((const float*)p)[i]
                 : __bfloat162float(((const __hip_bfloat16*)p)[i]);
}
__device__ inline float sigm(float x) { return 1.f / (1.f + expf(-x)); }

// ---------------- dtype probe: bf16 interpretation of fp32 data explodes ----------------
__global__ void probe_kernel(const void* __restrict__ seed, int* __restrict__ flag)
{
    __shared__ float red[256];
    int t = threadIdx.x;
    const __hip_bfloat16* p = (const __hip_bfloat16*)seed;
    float mx = 0.f;
    for (int k = 0; k < 16; ++k) {
        float v = fabsf(__bfloat162float(p[t * 16 + k]));
        if (!(v <= 1e30f)) v = 1e30f;
        mx = fmaxf(mx, v);
    }
    red[t] = mx;
    __syncthreads();
    if (t == 0) {
        float m = 0.f;
        for (int k = 0; k < 256; ++k) m = fmaxf(m, red[k]);
        *flag = (m > 1e10f) ? 1 : 0;   // 1 => inputs are float32
    }
}

// ---------------- prep: fp32 weights, T, edge lists, MFMA-swizzled bf16 weights ----------------
__global__ void prep_kernel(
    const void* __restrict__ wq, const void* __restrict__ bq,
    const void* __restrict__ wk, const void* __restrict__ bk,
    const void* __restrict__ wm, const void* __restrict__ bm,
    const void* __restrict__ w1, const void* __restrict__ b1,
    const void* __restrict__ w2, const void* __restrict__ b2,
    const void* __restrict__ wo, const void* __restrict__ bo,
    const void* __restrict__ gw, const void* __restrict__ gb,
    const void* __restrict__ wg, const void* __restrict__ bg,
    const void* __restrict__ wc, const void* __restrict__ bc,
    const int* __restrict__ edge, int E,
    float* __restrict__ Wf, float* __restrict__ Tf,
    int* __restrict__ counts, int* __restrict__ lists,
    __hip_bfloat16* __restrict__ swz,
    const int* __restrict__ flagp)
{
    int isf32 = *flagp;
    int idx = blockIdx.x * 256 + threadIdx.x;
    if (idx < WF_TOTAL) {
        int i = idx;
        const void* base;
        if (i < 512) base = wq;
        else if ((i -= 512) < 32) base = bq;
        else if ((i -= 32) < 512) base = wk;
        else if ((i -= 512) < 32) base = bk;
        else if ((i -= 32) < 2304) base = wm;
        else if ((i -= 2304) < 16) base = bm;
        else if ((i -= 16) < 4096) base = w1;
        else if ((i -= 4096) < 64) base = b1;
        else if ((i -= 64) < 4096) base = w2;
        else if ((i -= 4096) < 64) base = b2;
        else if ((i -= 64) < 64) base = wo;
        else if ((i -= 64) < 1) base = bo;
        else if ((i -= 1) < 16) base = gb;
        else if ((i -= 16) < 9216) base = wg;
        else if ((i -= 9216) < 32) base = bg;
        else if ((i -= 32) < 4608) base = wc;
        else { i -= 4608; base = bc; }
        Wf[idx] = loadf(base, i, isf32);
    } else if (idx < WF_TOTAL + 4096) {
        int i = idx - WF_TOTAL;
        int c = i >> 8, pix = i & 255;
        int y = pix >> 4, x = pix & 15;
        float s = 0.f;
        for (int ky = 0; ky < 3; ++ky)
            for (int kx = 0; kx < 3; ++kx) {
                int yy = y + ky - 1, xx = x + kx - 1;
                if (yy >= 0 && yy < 16 && xx >= 0 && xx < 16)
                    s += loadf(gw, c * 9 + ky * 3 + kx, isf32);
            }
        Tf[i] = s;
    } else if (idx < WF_TOTAL + 4096 + Nt) {
        int i = idx - WF_TOTAL - 4096;
        int deg = 0;
        for (int e = 0; e < E; ++e)
            if (edge[2 * e] == i) { if (deg < 8) lists[i * 8 + deg] = e; ++deg; }
        counts[i] = deg < 8 ? deg : 8;
    } else if (idx < WF_TOTAL + 4096 + Nt + SWZ_TOTAL) {
        // B-frag swizzle: element j of lane's frag holds B[k=(lane>>4)*8+j][n=lane&15]
        int j = idx - (WF_TOTAL + 4096 + Nt);
        float val;
        if (j < 9216) {                       // WgS: 9 shifts x 2 ntiles
            int sn = j >> 9, rem = j & 511;
            int ln = rem >> 3, jj = rem & 7;
            int s = sn >> 1, nt = sn & 1;
            int ci = (ln >> 4) * 8 + jj;
            int co = nt * 16 + (ln & 15);
            val = loadf(wg, co * 288 + ci * 9 + s, isf32);
        } else if (j < 9216 + 4608) {         // WcS: 9 shifts x 1 ntile
            int j1 = j - 9216;
            int s = j1 >> 9, rem = j1 & 511;
            int ln = rem >> 3, jj = rem & 7;
            int ci = (ln >> 4) * 8 + jj;
            int co = ln & 15;
            val = loadf(wc, co * 288 + ci * 9 + s, isf32);
        } else {                              // WmS: 5 shift-pairs (K=32 = 2 shifts x 16 ci)
            int j2 = j - 13824;
            int sp = j2 >> 9, rem = j2 & 511;
            int ln = rem >> 3, jj = rem & 7;
            int k = (ln >> 4) * 8 + jj;
            int s = sp * 2 + (k >> 4);
            int ci = k & 15;
            int co = ln & 15;
            val = (s <= 8) ? loadf(wm, co * 144 + ci * 9 + s, isf32) : 0.f;
        }
        swz[j] = __float2bfloat16(val);
    }
}

// ---------------- unpack: seed (B,C,128,128) -> X (B,N,C,16,16) fp32 ----------------
__global__ void unpack_kernel(const void* __restrict__ seed, float* __restrict__ X,
                              const int* __restrict__ flagp)
{
    int isf32 = *flagp;
    int idx = blockIdx.x * 256 + threadIdx.x;
    int pix = idx & 255;
    int rest = idx >> 8;
    int c = rest & 15; rest >>= 4;
    int n = rest & 63; int b = rest >> 6;
    int p = n >> 3, q = n & 7;
    int y = pix >> 4, x = pix & 15;
    X[idx] = loadf(seed, ((b * 16 + c) * 128 + p * 16 + y) * 128 + q * 16 + x, isf32);
}

// ---------------- pack: X fp32 -> out (B,C,128,128) ----------------
__global__ void pack_kernel(const float* __restrict__ X, void* __restrict__ out,
                            const int* __restrict__ flagp)
{
    int isf32 = *flagp;
    int idx = blockIdx.x * 256 + threadIdx.x;
    int xx = idx & 127;
    int rest = idx >> 7;
    int yy = rest & 127; rest >>= 7;
    int c = rest & 15; int b = rest >> 4;
    int p = yy >> 4, q = xx >> 4;
    int n = p * 8 + q;
    float v = X[(((b * 64 + n) * 16 + c) << 8) + (yy & 15) * 16 + (xx & 15)];
    if (isf32) ((float*)out)[idx] = v;
    else ((__hip_bfloat16*)out)[idx] = __float2bfloat16(v);
}

// ---------------- fused conv_m (MFMA) + patch stats + q/k ----------------
__global__ __launch_bounds__(256) void convm_stats_kernel(
    const float* __restrict__ X,
    const __hip_bfloat16* __restrict__ WmS, const float* __restrict__ bmf,
    const float* __restrict__ Wq, const float* __restrict__ bqf,
    const float* __restrict__ Wk, const float* __restrict__ bkf,
    __hip_bfloat16* __restrict__ M, float* __restrict__ qv, float* __restrict__ kv)
{
    __shared__ __align__(16) short sT[324 * 16];   // [pix_pad][ci] bf16
    __shared__ float red[256];
    __shared__ float xm[16];
    int bn = blockIdx.x;
    int t = threadIdx.x;
    const float* xbase = X + bn * 4096;

    // stage bf16 tile (pix-major, ch-minor), zero pad
    for (int idx = t; idx < 5184; idx += 256) {
        int ch = idx / 324, p = idx - ch * 324;
        int yy = p / 18 - 1, xx = p % 18 - 1;
        float v = 0.f;
        if (yy >= 0 && yy < 16 && xx >= 0 && xx < 16) v = xbase[ch * 256 + yy * 16 + xx];
        sT[p * 16 + ch] = f2bs(v);
    }
    // stats partial: thread (c,s) sums 16 pixels of channel c, column s
    {
        int c = t >> 4, s = t & 15;
        float acc = 0.f;
#pragma unroll
        for (int k = 0; k < 16; ++k) acc += xbase[c * 256 + k * 16 + s];
        red[t] = acc;
    }
    __syncthreads();
    if (t < 16) {
        float m = 0.f;
#pragma unroll
        for (int k = 0; k < 16; ++k) m += red[t * 16 + k];
        xm[t] = m * (1.0f / 256.0f);
    }
    __syncthreads();
    if (t < 32) {
        float a = bqf[t];
#pragma unroll
        for (int c2 = 0; c2 < 16; ++c2) a += xm[c2] * Wq[c2 * 32 + t];
        qv[bn * 32 + t] = a;
    } else if (t < 64) {
        int d = t - 32;
        float a = bkf[d];
#pragma unroll
        for (int c2 = 0; c2 < 16; ++c2) a += xm[c2] * Wk[c2 * 32 + d];
        kv[bn * 32 + d] = a;
    }

    // conv via MFMA: 5 K-chunks (shift pairs) x 4 Mtiles per wave
    int lane = t & 63, wv = t >> 6, quad = lane >> 4, n16 = lane & 15;
    const short* wp = (const short*)WmS;
    float bmv = bmf[n16];
    f32x4 acc[4];
#pragma unroll
    for (int mt = 0; mt < 4; ++mt) acc[mt] = (f32x4){bmv, bmv, bmv, bmv};
#pragma unroll
    for (int sp = 0; sp < 5; ++sp) {
        bf16x8 Bf = *(const bf16x8*)(wp + sp * 512 + lane * 8);
        int s2 = sp * 2 + (quad >> 1);
        if (s2 > 8) s2 = 8;                    // phantom shift: B is zero there
        int ky = s2 / 3, kx = s2 - ky * 3;
        int cib = (quad & 1) * 8;
#pragma unroll
        for (int mt = 0; mt < 4; ++mt) {
            int y = wv * 4 + mt;               // Mtile == image row
            bf16x8 A = *(const bf16x8*)(sT + ((y + ky) * 18 + n16 + kx) * 16 + cib);
            acc[mt] = __builtin_amdgcn_mfma_f32_16x16x32_bf16(A, Bf, acc[mt], 0, 0, 0);
        }
    }
    // write M bf16: C/D layout row=quad*4+reg (x), col=n16 (co)
    __hip_bfloat16* mp = M + bn * 4096 + n16 * 256;
#pragma unroll
    for (int mt = 0; mt < 4; ++mt) {
        int y = wv * 4 + mt;
#pragma unroll
        for (int r = 0; r < 4; ++r)
            mp[y * 16 + quad * 4 + r] = __float2bfloat16(acc[mt][r]);
    }
}

// ---------------- edge MLP: one wave per (b, edge) ----------------
__global__ __launch_bounds__(256) void edge_mlp_kernel(
    const int* __restrict__ edge, int E,
    const float* __restrict__ qv, const float* __restrict__ kv,
    const float* __restrict__ W1, const float* __restrict__ b1f,
    const float* __restrict__ W2, const float* __restrict__ b2f,
    const float* __restrict__ Wo, const float* __restrict__ bof,
    float* __restrict__ ev)
{
    int wave = (blockIdx.x * 256 + threadIdx.x) >> 6;
    int lane = threadIdx.x & 63;
    if (wave >= Bt * 224) return;
    int b = wave / E, e = wave % E;
    int ei = edge[2 * e], ej = edge[2 * e + 1];
    float h0 = (lane < 32) ? qv[(b * Nt + ei) * 32 + lane]
                           : kv[(b * Nt + ej) * 32 + (lane - 32)];
    float a1 = b1f[lane];
    for (int j = 0; j < 64; ++j) {
        float v = __shfl(h0, j, 64);
        a1 += v * W1[j * 64 + lane];
    }
    a1 = fmaxf(a1, 0.f);
    float a2 = b2f[lane];
    for (int j = 0; j < 64; ++j) {
        float v = __shfl(a1, j, 64);
        a2 += v * W2[j * 64 + lane];
    }
    a2 = fmaxf(a2, 0.f);
    float pe = a2 * Wo[lane];
    for (int off = 32; off; off >>= 1) pe += __shfl_down(pe, off, 64);
    if (lane == 0) ev[wave] = pe + bof[0];
}

// ---------------- fused aggregate + MFMA conv-GRU (per patch, in-place X) ----------------
__global__ __launch_bounds__(256) void gru_kernel(
    float* __restrict__ X, const __hip_bfloat16* __restrict__ M,
    const float* __restrict__ ev, const float* __restrict__ Tf,
    const float* __restrict__ gbf,
    const __hip_bfloat16* __restrict__ WgS, const float* __restrict__ bgf,
    const __hip_bfloat16* __restrict__ WcS, const float* __restrict__ bcf,
    const int* __restrict__ edge, const int* __restrict__ counts,
    const int* __restrict__ lists, int E)
{
    __shared__ __align__(16) short sAH[324 * 32];  // [pix_pad][32ch]: ch0-15=M_agg, ch16-31=h (later r*h)
    int bn = blockIdx.x, b = bn >> 6, i = bn & 63;
    int t = threadIdx.x;
    float* xbase = X + bn * 4096;

    // phase 1: h -> ch16..31 (bf16), zeros -> ch0..15 (pad rows of agg)
    for (int idx = t; idx < 5184; idx += 256) {
        int ch = idx / 324, p = idx - ch * 324;
        int yy = p / 18 - 1, xx = p % 18 - 1;
        float hv = 0.f;
        if (yy >= 0 && yy < 16 && xx >= 0 && xx < 16) hv = xbase[ch * 256 + yy * 16 + xx];
        sAH[p * 32 + 16 + ch] = f2bs(hv);
        sAH[p * 32 + ch] = 0;
    }
    // aggregation in registers: thread t owns pixel t, all 16 channels
    float racc[16];
#pragma unroll
    for (int c = 0; c < 16; ++c) racc[c] = 0.f;
    {
        float tf[16], gbl[16];
#pragma unroll
        for (int c = 0; c < 16; ++c) { tf[c] = Tf[c * 256 + t]; gbl[c] = gbf[c]; }
        int deg = counts[i];
        for (int ii = 0; ii < deg; ++ii) {
            int e = lists[i * 8 + ii];
            int ej = edge[2 * e + 1];
            float evv = ev[b * E + e];
            const __hip_bfloat16* mp = M + (b * 64 + ej) * 4096;
#pragma unroll
            for (int c = 0; c < 16; ++c)
                racc[c] += sigm(evv * tf[c] + gbl[c]) * bf2f(mp[c * 256 + t]);
        }
    }
    __syncthreads();
    {   // write M_agg bf16 into ch0..15 of own pixel: two 16B LDS writes
        int p = ((t >> 4) + 1) * 18 + (t & 15) + 1;
        bf16x8 v0, v1;
#pragma unroll
        for (int c = 0; c < 8; ++c) { v0[c] = f2bs(racc[c]); v1[c] = f2bs(racc[8 + c]); }
        *(bf16x8*)(sAH + p * 32) = v0;
        *(bf16x8*)(sAH + p * 32 + 8) = v1;
    }
    __syncthreads();

    int lane = t & 63, wv = t >> 6, quad = lane >> 4, n16 = lane & 15;
    const short* wgp = (const short*)WgS;
    const short* wcp = (const short*)WcS;

    // zr conv: 9 shifts x (2 ntiles x 4 Mtiles) MFMA
    float bz = bgf[n16], br = bgf[16 + n16];
    f32x4 accZ[4], accR[4];
#pragma unroll
    for (int mt = 0; mt < 4; ++mt) {
        accZ[mt] = (f32x4){bz, bz, bz, bz};
        accR[mt] = (f32x4){br, br, br, br};
    }
#pragma unroll
    for (int s = 0; s < 9; ++s) {
        int ky = s / 3, kx = s - ky * 3;
        bf16x8 B0 = *(const bf16x8*)(wgp + (s * 2 + 0) * 512 + lane * 8);
        bf16x8 B1 = *(const bf16x8*)(wgp + (s * 2 + 1) * 512 + lane * 8);
#pragma unroll
        for (int mt = 0; mt < 4; ++mt) {
            int y = wv * 4 + mt;
            bf16x8 A = *(const bf16x8*)(sAH + ((y + ky) * 18 + n16 + kx) * 32 + quad * 8);
            accZ[mt] = __builtin_amdgcn_mfma_f32_16x16x32_bf16(A, B0, accZ[mt], 0, 0, 0);
            accR[mt] = __builtin_amdgcn_mfma_f32_16x16x32_bf16(A, B1, accR[mt], 0, 0, 0);
        }
    }
    // z, r, h, r*h  (C/D: pixel = Mtile*16 + quad*4 + reg; co = n16)
    float zf[16], hf[16], rhs[16];
#pragma unroll
    for (int mt = 0; mt < 4; ++mt) {
        int y = wv * 4 + mt;
#pragma unroll
        for (int r = 0; r < 4; ++r) {
            int k = mt * 4 + r;
            int pp = (y + 1) * 18 + quad * 4 + r + 1;
            hf[k] = bs2f(sAH[pp * 32 + 16 + n16]);
            zf[k] = sigm(accZ[mt][r]);
            rhs[k] = sigm(accR[mt][r]) * hf[k];
        }
    }
    __syncthreads();
#pragma unroll
    for (int mt = 0; mt < 4; ++mt) {
        int y = wv * 4 + mt;
#pragma unroll
        for (int r = 0; r < 4; ++r)
            sAH[((y + 1) * 18 + quad * 4 + r + 1) * 32 + 16 + n16] = f2bs(rhs[mt * 4 + r]);
    }
    __syncthreads();

    // cand conv: 9 shifts x 4 Mtiles
    float bc = bcf[n16];
    f32x4 accC[4];
#pragma unroll
    for (int mt = 0; mt < 4; ++mt) accC[mt] = (f32x4){bc, bc, bc, bc};
#pragma unroll
    for (int s = 0; s < 9; ++s) {
        int ky = s / 3, kx = s - ky * 3;
        bf16x8 Bc = *(const bf16x8*)(wcp + s * 512 + lane * 8);
#pragma unroll
        for (int mt = 0; mt < 4; ++mt) {
            int y = wv * 4 + mt;
            bf16x8 A = *(const bf16x8*)(sAH + ((y + ky) * 18 + n16 + kx) * 32 + quad * 8);
            accC[mt] = __builtin_amdgcn_mfma_f32_16x16x32_bf16(A, Bc, accC[mt], 0, 0, 0);
        }
    }
    // epilogue: X = (1-z)*h + z*tanh(cand)
#pragma unroll
    for (int mt = 0; mt < 4; ++mt) {
        int y = wv * 4 + mt;
#pragma unroll
        for (int r = 0; r < 4; ++r) {
            int k = mt * 4 + r;
            float cand = tanhf(accC[mt][r]);
            xbase[n16 * 256 + y * 16 + quad * 4 + r] = (1.f - zf[k]) * hf[k] + zf[k] * cand;
        }
    }
}

extern "C" void kernel_launch(void* const* d_in, const int* in_sizes, int n_in,
                              void* d_out, int out_size, void* d_ws, size_t ws_size,
                              hipStream_t stream)
{
    const void* seed = d_in[0];
    const int* edge = (const int*)d_in[1];
    const int E = in_sizes[1] / 2;  // 224
    const int XTOT = Bt * Nt * Ct * 256;  // 4,194,304

    float* ws = (float*)d_ws;
    float* Xf = ws;                       // 4,194,304
    float* qv = Xf + XTOT;                // 32768
    float* kv = qv + Bt * Nt * Dt;        // 32768
    float* ev = kv + Bt * Nt * Dt;        // 3584
    float* Tf = ev + Bt * 224;            // 4096
    float* Wf = Tf + 4096;                // 25681
    int* flag = (int*)(Wf + WF_TOTAL);    // 1
    int* counts = flag + 64;
    int* lists = counts + 64;             // 512
    __hip_bfloat16* swz = (__hip_bfloat16*)(ws + 4293888);  // 16B-aligned, 16384 bf16

    __hip_bfloat16* Mb = (__hip_bfloat16*)d_out;  // M scratch; pack overwrites last

    float* Wqf = Wf;
    float* bqf = Wqf + 512;
    float* Wkf = bqf + 32;
    float* bkf = Wkf + 512;
    float* Wmf = bkf + 32;
    float* bmf = Wmf + 2304;
    float* W1f = bmf + 16;
    float* b1f = W1f + 4096;
    float* W2f = b1f + 64;
    float* b2f = W2f + 4096;
    float* Wof = b2f + 64;
    float* bof = Wof + 64;
    float* gbf = bof + 1;
    float* Wgf = gbf + 16;
    float* bgf = Wgf + 9216;
    float* Wcf = bgf + 32;
    float* bcf = Wcf + 4608;

    __hip_bfloat16* WgS = swz;
    __hip_bfloat16* WcS = swz + 9216;
    __hip_bfloat16* WmS = swz + 13824;

    probe_kernel<<<1, 256, 0, stream>>>(seed, flag);

    int prep_blocks = (WF_TOTAL + 4096 + Nt + SWZ_TOTAL + 255) / 256;
    prep_kernel<<<prep_blocks, 256, 0, stream>>>(
        d_in[2], d_in[3], d_in[4], d_in[5], d_in[6], d_in[7], d_in[8], d_in[9],
        d_in[10], d_in[11], d_in[12], d_in[13], d_in[14], d_in[15], d_in[16],
        d_in[17], d_in[18], d_in[19],
        edge, E, Wf, Tf, counts, lists, swz, flag);

    unpack_kernel<<<XTOT / 256, 256, 0, stream>>>(seed, Xf, flag);

    int mlp_blocks = (Bt * E * 64 + 255) / 256;
    for (int it = 0; it < KITERt; ++it) {
        convm_stats_kernel<<<Bt * Nt, 256, 0, stream>>>(Xf, WmS, bmf, Wqf, bqf, Wkf, bkf,
                                                        Mb, qv, kv);
        edge_mlp_kernel<<<mlp_blocks, 256, 0, stream>>>(edge, E, qv, kv, W1f, b1f, W2f, b2f,
                                                        Wof, bof, ev);
        gru_kernel<<<Bt * Nt, 256, 0, stream>>>(Xf, Mb, ev, Tf, gbf, WgS, bgf, WcS, bcf,
                                                edge, counts, lists, E);
    }

    pack_kernel<<<XTOT / 256, 256, 0, stream>>>(Xf, d_out, flag);
}

// Round 5
// 348.981 us; speedup vs baseline: 4.5848x; 1.1596x over previous
//
#include <hip/hip_runtime.h>
#include <hip/hip_bf16.h>

#define Bt 16
#define Ct 16
#define Nt 64
#define KITERt 4

// ---------- fp32 weight block offsets (floats) ----------
// wq@0(512) bq@512(32) wk@544(512) bk@1056(32) wm@1088(2304) bm@3392(16)
// w1@3408(4096) b1@7504(64) w2@7568(4096) b2@11664(64) wo@11728(64) bo@11792(1)
// gb@11793(16) wg@11809(9216) bg@21025(32) wc@21057(4608) bc@25665(16)
#define WF_TOTAL 25681
// swizzled bf16 MFMA B-frags: WgS 9216 | WcS 4608 | WmS 2560
#define SWZ_TOTAL 16384
#define SAH_STRIDE 40   // shorts per padded pixel row: 80B = 20 banks -> 2-way (free)

typedef __attribute__((ext_vector_type(8))) short bf16x8;
typedef __attribute__((ext_vector_type(4))) float f32x4;

__device__ inline float bf2f(__hip_bfloat16 v) { return __bfloat162float(v); }
__device__ inline short f2bs(float f) {
    __hip_bfloat16 h = __float2bfloat16(f);
    short s; __builtin_memcpy(&s, &h, 2); return s;
}
__device__ inline float bs2f(short s) {
    __hip_bfloat16 h; __builtin_memcpy(&h, &s, 2);
    return __bfloat162float(h);
}
__device__ inline float loadf(const void* p, int i, int isf32) {
    return isf32 ? ((const float*)p)[i]
                 : __bfloat162float(((const __hip_bfloat16*)p)[i]);
}
__device__ inline float sigm(float x) {
    return __builtin_amdgcn_rcpf(1.f + __expf(-x));
}
__device__ inline float tanh_fast(float x) {
    float e = __expf(2.f * x);              // inf-safe: rcp(inf)=0 -> 1; e=0 -> -1
    return 1.f - 2.f * __builtin_amdgcn_rcpf(e + 1.f);
}

// ---------------- dtype probe ----------------
__global__ void probe_kernel(const void* __restrict__ seed, int* __restrict__ flag)
{
    __shared__ float red[256];
    int t = threadIdx.x;
    const __hip_bfloat16* p = (const __hip_bfloat16*)seed;
    float mx = 0.f;
    for (int k = 0; k < 16; ++k) {
        float v = fabsf(__bfloat162float(p[t * 16 + k]));
        if (!(v <= 1e30f)) v = 1e30f;
        mx = fmaxf(mx, v);
    }
    red[t] = mx;
    __syncthreads();
    if (t == 0) {
        float m = 0.f;
        for (int k = 0; k < 256; ++k) m = fmaxf(m, red[k]);
        *flag = (m > 1e10f) ? 1 : 0;   // 1 => inputs are float32
    }
}

// ---------------- prep: fp32 weights, C-layout T, edge lists, swizzled bf16 weights ----------------
__global__ void prep_kernel(
    const void* __restrict__ wq, const void* __restrict__ bq,
    const void* __restrict__ wk, const void* __restrict__ bk,
    const void* __restrict__ wm, const void* __restrict__ bm,
    const void* __restrict__ w1, const void* __restrict__ b1,
    const void* __restrict__ w2, const void* __restrict__ b2,
    const void* __restrict__ wo, const void* __restrict__ bo,
    const void* __restrict__ gw, const void* __restrict__ gb,
    const void* __restrict__ wg, const void* __restrict__ bg,
    const void* __restrict__ wc, const void* __restrict__ bc,
    const int* __restrict__ edge, int E,
    float* __restrict__ Wf, float* __restrict__ Tswz,
    int* __restrict__ counts, int* __restrict__ lists,
    __hip_bfloat16* __restrict__ swz,
    const int* __restrict__ flagp)
{
    int isf32 = *flagp;
    int idx = blockIdx.x * 256 + threadIdx.x;
    if (idx < WF_TOTAL) {
        int i = idx;
        const void* base;
        if (i < 512) base = wq;
        else if ((i -= 512) < 32) base = bq;
        else if ((i -= 32) < 512) base = wk;
        else if ((i -= 512) < 32) base = bk;
        else if ((i -= 32) < 2304) base = wm;
        else if ((i -= 2304) < 16) base = bm;
        else if ((i -= 16) < 4096) base = w1;
        else if ((i -= 4096) < 64) base = b1;
        else if ((i -= 64) < 4096) base = w2;
        else if ((i -= 4096) < 64) base = b2;
        else if ((i -= 64) < 64) base = wo;
        else if ((i -= 64) < 1) base = bo;
        else if ((i -= 1) < 16) base = gb;
        else if ((i -= 16) < 9216) base = wg;
        else if ((i -= 9216) < 32) base = bg;
        else if ((i -= 32) < 4608) base = wc;
        else { i -= 4608; base = bc; }
        Wf[idx] = loadf(base, i, isf32);
    } else if (idx < WF_TOTAL + 4096) {
        // T in MFMA C-layout order: Tswz[t*16 + mt*4+r] = T[ch=n16][pix(wv,mt,quad,r)]
        int j = idx - WF_TOTAL;
        int tt = j >> 4, rr = j & 15;
        int wv = tt >> 6, ln = tt & 63, qd = ln >> 4, nn = ln & 15;
        int mt = rr >> 2, r2 = rr & 3;
        int pix = (wv * 4 + mt) * 16 + qd * 4 + r2;
        int y = pix >> 4, x = pix & 15;
        float s = 0.f;
        for (int ky = 0; ky < 3; ++ky)
            for (int kx = 0; kx < 3; ++kx) {
                int yy = y + ky - 1, xx = x + kx - 1;
                if (yy >= 0 && yy < 16 && xx >= 0 && xx < 16)
                    s += loadf(gw, nn * 9 + ky * 3 + kx, isf32);
            }
        Tswz[j] = s;
    } else if (idx < WF_TOTAL + 4096 + Nt) {
        int i = idx - WF_TOTAL - 4096;
        int deg = 0;
        for (int e = 0; e < E; ++e)
            if (edge[2 * e] == i) { if (deg < 8) lists[i * 8 + deg] = e; ++deg; }
        counts[i] = deg < 8 ? deg : 8;
    } else if (idx < WF_TOTAL + 4096 + Nt + SWZ_TOTAL) {
        // B-frag swizzle: element j of lane's frag holds B[k=(lane>>4)*8+j][n=lane&15]
        int j = idx - (WF_TOTAL + 4096 + Nt);
        float val;
        if (j < 9216) {                       // WgS: 9 shifts x 2 ntiles
            int sn = j >> 9, rem = j & 511;
            int ln = rem >> 3, jj = rem & 7;
            int s = sn >> 1, nt = sn & 1;
            int ci = (ln >> 4) * 8 + jj;
            int co = nt * 16 + (ln & 15);
            val = loadf(wg, co * 288 + ci * 9 + s, isf32);
        } else if (j < 9216 + 4608) {         // WcS: 9 shifts
            int j1 = j - 9216;
            int s = j1 >> 9, rem = j1 & 511;
            int ln = rem >> 3, jj = rem & 7;
            int ci = (ln >> 4) * 8 + jj;
            int co = ln & 15;
            val = loadf(wc, co * 288 + ci * 9 + s, isf32);
        } else {                              // WmS: 5 shift-pairs (K=32 = 2 shifts x 16 ci)
            int j2 = j - 13824;
            int sp = j2 >> 9, rem = j2 & 511;
            int ln = rem >> 3, jj = rem & 7;
            int k = (ln >> 4) * 8 + jj;
            int s = sp * 2 + (k >> 4);
            int ci = k & 15;
            int co = ln & 15;
            val = (s <= 8) ? loadf(wm, co * 144 + ci * 9 + s, isf32) : 0.f;
        }
        swz[j] = __float2bfloat16(val);
    }
}

// ---------------- unpack: seed -> Xb bf16 [b][n][pix][ch], plus initial q/k ----------------
__global__ __launch_bounds__(256) void unpack_kernel(
    const void* __restrict__ seed, __hip_bfloat16* __restrict__ Xb,
    float* __restrict__ qv, float* __restrict__ kv,
    const float* __restrict__ Wf, const int* __restrict__ flagp)
{
    __shared__ float sL[4096];
    __shared__ float red[256];
    __shared__ float xm[16];
    int bn = blockIdx.x, b = bn >> 6, n = bn & 63;
    int pq = n >> 3, qq = n & 7;
    int t = threadIdx.x, y = t >> 4, x = t & 15;
    int isf32 = *flagp;
    float v[16];
#pragma unroll
    for (int c = 0; c < 16; ++c)
        v[c] = loadf(seed, ((b * 16 + c) * 128 + pq * 16 + y) * 128 + qq * 16 + x, isf32);
    bf16x8 o0, o1;
#pragma unroll
    for (int c = 0; c < 8; ++c) { o0[c] = f2bs(v[c]); o1[c] = f2bs(v[8 + c]); }
    short* xo = (short*)(Xb + bn * 4096);
    *(bf16x8*)(xo + t * 16) = o0;
    *(bf16x8*)(xo + t * 16 + 8) = o1;
#pragma unroll
    for (int c = 0; c < 16; ++c) sL[t * 16 + c] = v[c];
    __syncthreads();
    {
        int c = t >> 4, s = t & 15;
        float acc = 0.f;
#pragma unroll
        for (int k = 0; k < 16; ++k) acc += sL[(k * 16 + s) * 16 + c];
        red[t] = acc;
    }
    __syncthreads();
    if (t < 16) {
        float m = 0.f;
#pragma unroll
        for (int k = 0; k < 16; ++k) m += red[t * 16 + k];
        xm[t] = m * (1.0f / 256.0f);
    }
    __syncthreads();
    if (t < 64) {
        int d = t & 31;
        const float* W = (t < 32) ? Wf : Wf + 544;
        float a = (t < 32) ? Wf[512 + d] : Wf[1056 + d];
#pragma unroll
        for (int c = 0; c < 16; ++c) a += xm[c] * W[c * 32 + d];
        if (t < 32) qv[bn * 32 + d] = a; else kv[bn * 32 + d] = a;
    }
}

// ---------------- pack: Xb bf16 [pix][ch] -> out (B,C,128,128) ----------------
__global__ void pack_kernel(const __hip_bfloat16* __restrict__ Xb, void* __restrict__ out,
                            const int* __restrict__ flagp)
{
    int isf32 = *flagp;
    int idx = blockIdx.x * 256 + threadIdx.x;
    int xx = idx & 127;
    int rest = idx >> 7;
    int yy = rest & 127; rest >>= 7;
    int c = rest & 15; int b = rest >> 4;
    int n = (yy >> 4) * 8 + (xx >> 4);
    float v = bf2f(Xb[((b * 64 + n) * 256 + (yy & 15) * 16 + (xx & 15)) * 16 + c]);
    if (isf32) ((float*)out)[idx] = v;
    else ((__hip_bfloat16*)out)[idx] = __float2bfloat16(v);
}

// ---------------- fully fused iteration: one block per (b, patch) ----------------
// Double-buffered: reads ONLY Xin/qin/kin, writes ONLY Xout/qout/kout.
__global__ __launch_bounds__(256) void iter_kernel(
    const __hip_bfloat16* __restrict__ Xin, __hip_bfloat16* __restrict__ Xout,
    const float* __restrict__ qin, const float* __restrict__ kin,
    float* __restrict__ qout, float* __restrict__ kout,
    const float* __restrict__ Tswz,
    const __hip_bfloat16* __restrict__ WmS,
    const __hip_bfloat16* __restrict__ WgS,
    const __hip_bfloat16* __restrict__ WcS,
    const float* __restrict__ Wf,
    const int* __restrict__ edge, const int* __restrict__ counts,
    const int* __restrict__ lists, int E)
{
    __shared__ __align__(16) short sAH[324 * SAH_STRIDE];  // [pad-pix][ch0-15=Magg, ch16-31=h/rh]
    __shared__ float evs[8];
    __shared__ int ejs[8];
    __shared__ float xred[64];
    int bn = blockIdx.x, b = bn >> 6, i = bn & 63;
    int t = threadIdx.x, lane = t & 63, wv = t >> 6;
    int quad = lane >> 4, n16 = lane & 15;

    // phase 0: per-lane constants
    float T_lane[16];
#pragma unroll
    for (int r = 0; r < 16; ++r) T_lane[r] = Tswz[t * 16 + r];
    float gb_l = Wf[11793 + n16];
    float bm_l = Wf[3392 + n16];

    const short* xown = (const short*)(Xin + bn * 4096);

    // phase 1: stage own h into sAH ch16-31; zero border rows
    for (int p = t; p < 324; p += 256) {
        int yy = p / 18 - 1, xx = p % 18 - 1;
        short* row = sAH + p * SAH_STRIDE;
        if ((unsigned)yy < 16u && (unsigned)xx < 16u) {
            const short* src = xown + (yy * 16 + xx) * 16;
            *(bf16x8*)(row + 16) = *(const bf16x8*)(src);
            *(bf16x8*)(row + 24) = *(const bf16x8*)(src + 8);
        } else {
            bf16x8 z = {0, 0, 0, 0, 0, 0, 0, 0};
            *(bf16x8*)(row) = z;      *(bf16x8*)(row + 8) = z;
            *(bf16x8*)(row + 16) = z; *(bf16x8*)(row + 24) = z;
        }
    }

    // phase 2: edge MLP, one wave per incoming edge
    int deg = counts[i];
    if (wv < deg) {
        int e = lists[i * 8 + wv];
        int ej = edge[2 * e + 1];
        float h0 = (lane < 32) ? qin[bn * 32 + lane]
                               : kin[(b * 64 + ej) * 32 + (lane - 32)];
        const float* W1 = Wf + 3408;
        const float* W2 = Wf + 7568;
        float a1 = Wf[7504 + lane];
#pragma unroll
        for (int j = 0; j < 64; ++j) a1 += __shfl(h0, j, 64) * W1[j * 64 + lane];
        a1 = fmaxf(a1, 0.f);
        float a2 = Wf[11664 + lane];
#pragma unroll
        for (int j = 0; j < 64; ++j) a2 += __shfl(a1, j, 64) * W2[j * 64 + lane];
        a2 = fmaxf(a2, 0.f);
        float pe = a2 * Wf[11728 + lane];
#pragma unroll
        for (int off = 32; off; off >>= 1) pe += __shfl_down(pe, off, 64);
        if (lane == 0) { evs[wv] = pe + Wf[11792]; ejs[wv] = ej; }
    }
    __syncthreads();

    // phase 3: neighbor M-convs (A-frags straight from global Xin) + gated accumulate
    f32x4 magg[4];
#pragma unroll
    for (int mt = 0; mt < 4; ++mt) magg[mt] = (f32x4){0.f, 0.f, 0.f, 0.f};
    for (int ii = 0; ii < deg; ++ii) {
        int ej = ejs[ii];
        float evv = evs[ii];
        const short* xb_n = (const short*)(Xin + (b * 64 + ej) * 4096);
        f32x4 acc[4];
#pragma unroll
        for (int mt = 0; mt < 4; ++mt) acc[mt] = (f32x4){bm_l, bm_l, bm_l, bm_l};
#pragma unroll
        for (int sp = 0; sp < 5; ++sp) {
            bf16x8 Bf = *(const bf16x8*)((const short*)WmS + sp * 512 + lane * 8);
            int s2 = sp * 2 + (quad >> 1);
            if (s2 > 8) s2 = 8;                      // phantom shift: B half is zero
            int ky = s2 / 3 - 1, kx = s2 - (s2 / 3) * 3 - 1;
            int cib = (quad & 1) * 8;
#pragma unroll
            for (int mt = 0; mt < 4; ++mt) {
                int py = wv * 4 + mt + ky, px = n16 + kx;
                bf16x8 A = {0, 0, 0, 0, 0, 0, 0, 0};
                if ((unsigned)py < 16u && (unsigned)px < 16u)
                    A = *(const bf16x8*)(xb_n + (py * 16 + px) * 16 + cib);
                acc[mt] = __builtin_amdgcn_mfma_f32_16x16x32_bf16(A, Bf, acc[mt], 0, 0, 0);
            }
        }
#pragma unroll
        for (int mt = 0; mt < 4; ++mt)
#pragma unroll
            for (int r = 0; r < 4; ++r)
                magg[mt][r] += sigm(evv * T_lane[mt * 4 + r] + gb_l) * acc[mt][r];
    }
    // phase 4: M_agg -> sAH ch0-15 (every interior (pixel,ch) written exactly once)
#pragma unroll
    for (int mt = 0; mt < 4; ++mt)
#pragma unroll
        for (int r = 0; r < 4; ++r) {
            int p = (wv * 4 + mt + 1) * 18 + quad * 4 + r + 1;
            sAH[p * SAH_STRIDE + n16] = f2bs(magg[mt][r]);
        }
    __syncthreads();

    // phase 5: zr conv (K=32 = [Magg;h] channels), 9 shifts x 2 ntiles x 4 Mtiles
    float bz = Wf[21025 + n16], br = Wf[21025 + 16 + n16];
    f32x4 accZ[4], accR[4];
#pragma unroll
    for (int mt = 0; mt < 4; ++mt) {
        accZ[mt] = (f32x4){bz, bz, bz, bz};
        accR[mt] = (f32x4){br, br, br, br};
    }
#pragma unroll
    for (int s = 0; s < 9; ++s) {
        int ky = s / 3, kx = s - (s / 3) * 3;
        bf16x8 B0 = *(const bf16x8*)((const short*)WgS + (s * 2 + 0) * 512 + lane * 8);
        bf16x8 B1 = *(const bf16x8*)((const short*)WgS + (s * 2 + 1) * 512 + lane * 8);
#pragma unroll
        for (int mt = 0; mt < 4; ++mt) {
            int pc = (wv * 4 + mt + ky) * 18 + n16 + kx;
            bf16x8 A = *(const bf16x8*)(sAH + pc * SAH_STRIDE + quad * 8);
            accZ[mt] = __builtin_amdgcn_mfma_f32_16x16x32_bf16(A, B0, accZ[mt], 0, 0, 0);
            accR[mt] = __builtin_amdgcn_mfma_f32_16x16x32_bf16(A, B1, accR[mt], 0, 0, 0);
        }
    }
    // phase 6: z, r, h, r*h
    float zf[16], hf[16], rh[16];
#pragma unroll
    for (int mt = 0; mt < 4; ++mt)
#pragma unroll
        for (int r = 0; r < 4; ++r) {
            int k = mt * 4 + r;
            int ps = (wv * 4 + mt + 1) * 18 + quad * 4 + r + 1;
            hf[k] = bs2f(sAH[ps * SAH_STRIDE + 16 + n16]);
            zf[k] = sigm(accZ[mt][r]);
            rh[k] = sigm(accR[mt][r]) * hf[k];
        }
    __syncthreads();
#pragma unroll
    for (int mt = 0; mt < 4; ++mt)
#pragma unroll
        for (int r = 0; r < 4; ++r) {
            int ps = (wv * 4 + mt + 1) * 18 + quad * 4 + r + 1;
            sAH[ps * SAH_STRIDE + 16 + n16] = f2bs(rh[mt * 4 + r]);
        }
    __syncthreads();

    // phase 8: cand conv (K=32 = [Magg; r*h])
    float bcl = Wf[25665 + n16];
    f32x4 accC[4];
#pragma unroll
    for (int mt = 0; mt < 4; ++mt) accC[mt] = (f32x4){bcl, bcl, bcl, bcl};
#pragma unroll
    for (int s = 0; s < 9; ++s) {
        int ky = s / 3, kx = s - (s / 3) * 3;
        bf16x8 Bc = *(const bf16x8*)((const short*)WcS + s * 512 + lane * 8);
#pragma unroll
        for (int mt = 0; mt < 4; ++mt) {
            int pc = (wv * 4 + mt + ky) * 18 + n16 + kx;
            bf16x8 A = *(const bf16x8*)(sAH + pc * SAH_STRIDE + quad * 8);
            accC[mt] = __builtin_amdgcn_mfma_f32_16x16x32_bf16(A, Bc, accC[mt], 0, 0, 0);
        }
    }
    // phase 9: epilogue X = (1-z)h + z*tanh(cand); write bf16 Xout; channel sum for stats
    float ssum = 0.f;
    short* xo = (short*)(Xout + bn * 4096);
#pragma unroll
    for (int mt = 0; mt < 4; ++mt)
#pragma unroll
        for (int r = 0; r < 4; ++r) {
            int k = mt * 4 + r;
            float cand = tanh_fast(accC[mt][r]);
            float nx = (1.f - zf[k]) * hf[k] + zf[k] * cand;
            ssum += nx;
            int pix = (wv * 4 + mt) * 16 + quad * 4 + r;
            xo[pix * 16 + n16] = f2bs(nx);
        }
    // phase 10: q/k of NEW X (consumed by next launch)
    ssum += __shfl_xor(ssum, 16, 64);
    ssum += __shfl_xor(ssum, 32, 64);
    if (lane < 16) xred[wv * 16 + lane] = ssum;
    __syncthreads();
    if (t < 64) {
        int d = t & 31;
        const float* W = (t < 32) ? Wf : Wf + 544;
        float a = (t < 32) ? Wf[512 + d] : Wf[1056 + d];
#pragma unroll
        for (int c = 0; c < 16; ++c) {
            float xc = (xred[c] + xred[16 + c] + xred[32 + c] + xred[48 + c]) * (1.f / 256.f);
            a += xc * W[c * 32 + d];
        }
        if (t < 32) qout[bn * 32 + d] = a; else kout[bn * 32 + d] = a;
    }
}

extern "C" void kernel_launch(void* const* d_in, const int* in_sizes, int n_in,
                              void* d_out, int out_size, void* d_ws, size_t ws_size,
                              hipStream_t stream)
{
    const void* seed = d_in[0];
    const int* edge = (const int*)d_in[1];
    const int E = in_sizes[1] / 2;  // 224

    float* ws = (float*)d_ws;
    __hip_bfloat16* Xb0 = (__hip_bfloat16*)ws;       // 4,194,304 bf16 = 2,097,152 floats
    __hip_bfloat16* Xb1 = (__hip_bfloat16*)d_out;    // scratch X; pack overwrites at end
    float* qv0 = ws + 2097152;                       // 32768
    float* kv0 = qv0 + 32768;
    float* qv1 = kv0 + 32768;
    float* kv1 = qv1 + 32768;
    float* Tswz = kv1 + 32768;                       // 4096
    float* Wf = Tswz + 4096;                         // 25681
    int* flag = (int*)(Wf + WF_TOTAL);
    int* counts = flag + 16;
    int* lists = counts + 64;                        // 512
    __hip_bfloat16* swz = (__hip_bfloat16*)(ws + 2260000);  // 16B-aligned, 16384 bf16

    __hip_bfloat16* WgS = swz;
    __hip_bfloat16* WcS = swz + 9216;
    __hip_bfloat16* WmS = swz + 13824;

    probe_kernel<<<1, 256, 0, stream>>>(seed, flag);

    int prep_blocks = (WF_TOTAL + 4096 + Nt + SWZ_TOTAL + 255) / 256;
    prep_kernel<<<prep_blocks, 256, 0, stream>>>(
        d_in[2], d_in[3], d_in[4], d_in[5], d_in[6], d_in[7], d_in[8], d_in[9],
        d_in[10], d_in[11], d_in[12], d_in[13], d_in[14], d_in[15], d_in[16],
        d_in[17], d_in[18], d_in[19],
        edge, E, Wf, Tswz, counts, lists, swz, flag);

    unpack_kernel<<<Bt * Nt, 256, 0, stream>>>(seed, Xb0, qv0, kv0, Wf, flag);

    __hip_bfloat16* Xs[2] = {Xb0, Xb1};
    float* qs[2] = {qv0, qv1};
    float* ks[2] = {kv0, kv1};
    for (int it = 0; it < KITERt; ++it) {
        int in = it & 1, on = in ^ 1;
        iter_kernel<<<Bt * Nt, 256, 0, stream>>>(
            Xs[in], Xs[on], qs[in], ks[in], qs[on], ks[on],
            Tswz, WmS, WgS, WcS, Wf, edge, counts, lists, E);
    }

    // KITERt even -> final X parity is buffer 0 (ws); pack writes d_out last
    pack_kernel<<<out_size / 256, 256, 0, stream>>>(Xs[KITERt & 1], d_out, flag);
}

// Round 7
// 276.152 us; speedup vs baseline: 5.7939x; 1.2637x over previous
//
#include <hip/hip_runtime.h>
#include <hip/hip_bf16.h>

#define Bt 16
#define Ct 16
#define Nt 64
#define KITERt 4

// ---------- fp32 weight block offsets (floats) ----------
// wq@0(512) bq@512(32) wk@544(512) bk@1056(32) wm@1088(2304) bm@3392(16)
// w1@3408(4096) b1@7504(64) w2@7568(4096) b2@11664(64) wo@11728(64) bo@11792(1)
// gb@11793(16) wg@11809(9216) bg@21025(32) wc@21057(4608) bc@25665(16)
#define WF_TOTAL 25681
// swizzled bf16 MFMA B-frags: WgS 9216 | WcS 4608 | WmS 2560
#define SWZ_TOTAL 16384
#define SETUP_IDX (WF_TOTAL + 4096 + Nt + SWZ_TOTAL)
#define SAH_STRIDE 40   // shorts per padded pixel row: 80B = 20 banks -> 2-way (free)

typedef __attribute__((ext_vector_type(8))) short bf16x8;
typedef __attribute__((ext_vector_type(4))) float f32x4;

__device__ inline float bf2f(__hip_bfloat16 v) { return __bfloat162float(v); }
__device__ inline short f2bs(float f) {
    __hip_bfloat16 h = __float2bfloat16(f);
    short s; __builtin_memcpy(&s, &h, 2); return s;
}
__device__ inline float bs2f(short s) {
    __hip_bfloat16 h; __builtin_memcpy(&h, &s, 2);
    return __bfloat162float(h);
}
__device__ inline float loadf(const void* p, int i, int isf32) {
    return isf32 ? ((const float*)p)[i]
                 : __bfloat162float(((const __hip_bfloat16*)p)[i]);
}
__device__ inline float sigm(float x) {
    return __builtin_amdgcn_rcpf(1.f + __expf(-x));
}
__device__ inline float tanh_fast(float x) {
    float e = __expf(2.f * x);              // inf-safe: rcp(inf)=0 -> 1; e=0 -> -1
    return 1.f - 2.f * __builtin_amdgcn_rcpf(e + 1.f);
}

// Every thread decides the input dtype locally from 256 uniform samples of seed:
// bf16 reinterpretation of fp32 data explodes (P[all 128 mantissa-halves small] ~ 1e-14).
__device__ inline int detect_f32(const void* seed) {
    const __hip_bfloat16* p = (const __hip_bfloat16*)seed;
    float mx = 0.f;
#pragma unroll 8
    for (int k = 0; k < 256; ++k) {
        float v = fabsf(__bfloat162float(p[k]));
        if (!(v <= 1e30f)) v = 1e30f;
        mx = fmaxf(mx, v);
    }
    return mx > 1e10f ? 1 : 0;
}

// ---------------- setup: weights->fp32, Tswz, edge lists, swizzled bf16 weights,
// ---------------- unpack seed -> Xb bf16 [b][n][pix][ch], initial q/k, flag ----------------
__global__ __launch_bounds__(256) void setup_kernel(
    const void* __restrict__ seed,
    const void* __restrict__ wq, const void* __restrict__ bq,
    const void* __restrict__ wk, const void* __restrict__ bk,
    const void* __restrict__ wm, const void* __restrict__ bm,
    const void* __restrict__ w1, const void* __restrict__ b1,
    const void* __restrict__ w2, const void* __restrict__ b2,
    const void* __restrict__ wo, const void* __restrict__ bo,
    const void* __restrict__ gw, const void* __restrict__ gb,
    const void* __restrict__ wg, const void* __restrict__ bg,
    const void* __restrict__ wc, const void* __restrict__ bc,
    const int* __restrict__ edge, int E,
    float* __restrict__ Wf, float* __restrict__ Tswz,
    int* __restrict__ counts, int* __restrict__ lists,
    __hip_bfloat16* __restrict__ swz,
    short* __restrict__ Xb, float* __restrict__ qv0, float* __restrict__ kv0,
    int* __restrict__ flag)
{
    __shared__ float xred[64];
    int bn = blockIdx.x, t = threadIdx.x;
    int lane = t & 63, wv = t >> 6;
    int isf32 = detect_f32(seed);
    if (bn == 0 && t == 0) *flag = isf32;

    // ---- part 1: indexed weight prep ----
    int idx = bn * 256 + t;
    if (idx < WF_TOTAL) {
        int i = idx;
        const void* base;
        if (i < 512) base = wq;
        else if ((i -= 512) < 32) base = bq;
        else if ((i -= 32) < 512) base = wk;
        else if ((i -= 512) < 32) base = bk;
        else if ((i -= 32) < 2304) base = wm;
        else if ((i -= 2304) < 16) base = bm;
        else if ((i -= 16) < 4096) base = w1;
        else if ((i -= 4096) < 64) base = b1;
        else if ((i -= 64) < 4096) base = w2;
        else if ((i -= 4096) < 64) base = b2;
        else if ((i -= 64) < 64) base = wo;
        else if ((i -= 64) < 1) base = bo;
        else if ((i -= 1) < 16) base = gb;
        else if ((i -= 16) < 9216) base = wg;
        else if ((i -= 9216) < 32) base = bg;
        else if ((i -= 32) < 4608) base = wc;
        else { i -= 4608; base = bc; }
        Wf[idx] = loadf(base, i, isf32);
    } else if (idx < WF_TOTAL + 4096) {
        // T in MFMA C-layout order: Tswz[t*16 + mt*4+r] = T[ch=n16][pix(wv,mt,quad,r)]
        int j = idx - WF_TOTAL;
        int tt = j >> 4, rr = j & 15;
        int wv2 = tt >> 6, ln = tt & 63, qd = ln >> 4, nn = ln & 15;
        int mt = rr >> 2, r2 = rr & 3;
        int pix = (wv2 * 4 + mt) * 16 + qd * 4 + r2;
        int y = pix >> 4, x = pix & 15;
        float s = 0.f;
        for (int ky = 0; ky < 3; ++ky)
            for (int kx = 0; kx < 3; ++kx) {
                int yy = y + ky - 1, xx = x + kx - 1;
                if (yy >= 0 && yy < 16 && xx >= 0 && xx < 16)
                    s += loadf(gw, nn * 9 + ky * 3 + kx, isf32);
            }
        Tswz[j] = s;
    } else if (idx < WF_TOTAL + 4096 + Nt) {
        int i = idx - WF_TOTAL - 4096;
        int deg = 0;
        for (int e = 0; e < E; ++e)
            if (edge[2 * e] == i) { if (deg < 8) lists[i * 8 + deg] = e; ++deg; }
        counts[i] = deg < 8 ? deg : 8;
    } else if (idx < SETUP_IDX) {
        // B-frag swizzle: element j of lane's frag holds B[k=(lane>>4)*8+j][n=lane&15]
        int j = idx - (WF_TOTAL + 4096 + Nt);
        float val;
        if (j < 9216) {                       // WgS: 9 shifts x 2 ntiles
            int sn = j >> 9, rem = j & 511;
            int ln = rem >> 3, jj = rem & 7;
            int s = sn >> 1, nt = sn & 1;
            int ci = (ln >> 4) * 8 + jj;
            int co = nt * 16 + (ln & 15);
            val = loadf(wg, co * 288 + ci * 9 + s, isf32);
        } else if (j < 9216 + 4608) {         // WcS: 9 shifts
            int j1 = j - 9216;
            int s = j1 >> 9, rem = j1 & 511;
            int ln = rem >> 3, jj = rem & 7;
            int ci = (ln >> 4) * 8 + jj;
            int co = ln & 15;
            val = loadf(wc, co * 288 + ci * 9 + s, isf32);
        } else {                              // WmS: 5 shift-pairs (K=32 = 2 shifts x 16 ci)
            int j2 = j - 13824;
            int sp = j2 >> 9, rem = j2 & 511;
            int ln = rem >> 3, jj = rem & 7;
            int k = (ln >> 4) * 8 + jj;
            int s = sp * 2 + (k >> 4);
            int ci = k & 15;
            int co = ln & 15;
            val = (s <= 8) ? loadf(wm, co * 144 + ci * 9 + s, isf32) : 0.f;
        }
        swz[j] = __float2bfloat16(val);
    }

    // ---- part 2: unpack own patch bn + initial q/k (reads RAW inputs only) ----
    {
        int b = bn >> 6, n = bn & 63;
        int pq = n >> 3, qq = n & 7;
        int y = t >> 4, x = t & 15;
        float v[16];
#pragma unroll
        for (int c = 0; c < 16; ++c)
            v[c] = loadf(seed, ((b * 16 + c) * 128 + pq * 16 + y) * 128 + qq * 16 + x, isf32);
        bf16x8 o0, o1;
#pragma unroll
        for (int c = 0; c < 8; ++c) { o0[c] = f2bs(v[c]); o1[c] = f2bs(v[8 + c]); }
        short* xo = Xb + bn * 4096;
        *(bf16x8*)(xo + t * 16) = o0;
        *(bf16x8*)(xo + t * 16 + 8) = o1;
        // per-channel wave sums (butterfly)
#pragma unroll
        for (int c = 0; c < 16; ++c) {
            float s = v[c];
#pragma unroll
            for (int off = 1; off < 64; off <<= 1) s += __shfl_xor(s, off, 64);
            if (lane == c) xred[wv * 16 + c] = s;
        }
        __syncthreads();
        if (t < 64) {
            int d = t & 31;
            float a = (t < 32) ? loadf(bq, d, isf32) : loadf(bk, d, isf32);
#pragma unroll
            for (int c = 0; c < 16; ++c) {
                float xm = (xred[c] + xred[16 + c] + xred[32 + c] + xred[48 + c]) * (1.f / 256.f);
                a += xm * ((t < 32) ? loadf(wq, c * 32 + d, isf32)
                                    : loadf(wk, c * 32 + d, isf32));
            }
            if (t < 32) qv0[bn * 32 + d] = a; else kv0[bn * 32 + d] = a;
        }
    }
}

// ---------------- pack: Xb bf16 [pix][ch] -> out (B,C,128,128) ----------------
__global__ void pack_kernel(const short* __restrict__ Xb, void* __restrict__ out,
                            const int* __restrict__ flagp)
{
    int isf32 = *flagp;
    int idx = blockIdx.x * 256 + threadIdx.x;
    int xx = idx & 127;
    int rest = idx >> 7;
    int yy = rest & 127; rest >>= 7;
    int c = rest & 15; int b = rest >> 4;
    int n = (yy >> 4) * 8 + (xx >> 4);
    float v = bs2f(Xb[((b * 64 + n) * 256 + (yy & 15) * 16 + (xx & 15)) * 16 + c]);
    if (isf32) ((float*)out)[idx] = v;
    else ((__hip_bfloat16*)out)[idx] = __float2bfloat16(v);
}

// ---------------- fused iteration: one block per (b, patch) ----------------
// Double-buffered: reads ONLY Xin/qin/kin, writes ONLY Xout/qout/kout.
__global__ __launch_bounds__(256) void iter_kernel(
    const __hip_bfloat16* __restrict__ Xin, __hip_bfloat16* __restrict__ Xout,
    const float* __restrict__ qin, const float* __restrict__ kin,
    float* __restrict__ qout, float* __restrict__ kout,
    const float* __restrict__ Tswz,
    const short* __restrict__ WmS,
    const short* __restrict__ WgS,
    const short* __restrict__ WcS,
    const float* __restrict__ Wf,
    const int* __restrict__ edge, const int* __restrict__ counts,
    const int* __restrict__ lists, int E)
{
    __shared__ __align__(16) short sAH[324 * SAH_STRIDE];  // ch0-15=nbrX/Magg, ch16-31=h/rh
    __shared__ float evs[8];
    int bn = blockIdx.x, b = bn >> 6, i = bn & 63;
    int t = threadIdx.x, lane = t & 63, wv = t >> 6;
    int quad = lane >> 4, n16 = lane & 15;

    // ---- edge list + neighbor-0 prefetch (issued first: longest latency) ----
    int deg = counts[i];
    if (deg > 4) deg = 4;                    // grid graph: max degree 4
    int el[4], ejl[4];
#pragma unroll
    for (int ii = 0; ii < 4; ++ii) {
        int e = (ii < deg) ? lists[i * 8 + ii] : 0;
        el[ii] = e;
        ejl[ii] = (ii < deg) ? edge[2 * e + 1] : 0;
    }
    bf16x8 nbA0, nbA1, nbB0, nbB1;
    if (deg > 0) {
        const short* mp = (const short*)Xin + (b * 64 + ejl[0]) * 4096 + t * 16;
        nbA0 = *(const bf16x8*)(mp);
        nbA1 = *(const bf16x8*)(mp + 8);
    }

    // per-lane constants
    float T_lane[16];
#pragma unroll
    for (int r = 0; r < 16; ++r) T_lane[r] = Tswz[t * 16 + r];
    float gb_l = Wf[11793 + n16];
    float bm_l = Wf[3392 + n16];

    const short* xown = (const short*)Xin + bn * 4096;

    // ---- phase A: stage own h into ch16-31; zero borders (all 32 ch) ----
    for (int p = t; p < 324; p += 256) {
        int yy = p / 18 - 1, xx = p % 18 - 1;
        short* row = sAH + p * SAH_STRIDE;
        if ((unsigned)yy < 16u && (unsigned)xx < 16u) {
            const short* src = xown + (yy * 16 + xx) * 16;
            *(bf16x8*)(row + 16) = *(const bf16x8*)(src);
            *(bf16x8*)(row + 24) = *(const bf16x8*)(src + 8);
        } else {
            bf16x8 z = {0, 0, 0, 0, 0, 0, 0, 0};
            *(bf16x8*)(row) = z;      *(bf16x8*)(row + 8) = z;
            *(bf16x8*)(row + 16) = z; *(bf16x8*)(row + 24) = z;
        }
    }

    // ---- phase B: edge MLP, one wave per incoming edge (4 accumulators) ----
    if (wv < deg) {
        int ej = ejl[wv];
        float h0 = (lane < 32) ? qin[bn * 32 + lane]
                               : kin[(b * 64 + ej) * 32 + (lane - 32)];
        const float* W1 = Wf + 3408;
        const float* W2 = Wf + 7568;
        float p0 = 0.f, p1 = 0.f, p2 = 0.f, p3 = 0.f;
#pragma unroll
        for (int j = 0; j < 64; j += 4) {
            p0 += __shfl(h0, j + 0, 64) * W1[(j + 0) * 64 + lane];
            p1 += __shfl(h0, j + 1, 64) * W1[(j + 1) * 64 + lane];
            p2 += __shfl(h0, j + 2, 64) * W1[(j + 2) * 64 + lane];
            p3 += __shfl(h0, j + 3, 64) * W1[(j + 3) * 64 + lane];
        }
        float a1 = fmaxf(Wf[7504 + lane] + ((p0 + p1) + (p2 + p3)), 0.f);
        p0 = p1 = p2 = p3 = 0.f;
#pragma unroll
        for (int j = 0; j < 64; j += 4) {
            p0 += __shfl(a1, j + 0, 64) * W2[(j + 0) * 64 + lane];
            p1 += __shfl(a1, j + 1, 64) * W2[(j + 1) * 64 + lane];
            p2 += __shfl(a1, j + 2, 64) * W2[(j + 2) * 64 + lane];
            p3 += __shfl(a1, j + 3, 64) * W2[(j + 3) * 64 + lane];
        }
        float a2 = fmaxf(Wf[11664 + lane] + ((p0 + p1) + (p2 + p3)), 0.f);
        float pe = a2 * Wf[11728 + lane];
#pragma unroll
        for (int off = 32; off; off >>= 1) pe += __shfl_down(pe, off, 64);
        if (lane == 0) evs[wv] = pe + Wf[11792];
    }
    __syncthreads();   // h staged + evs ready

    // ---- phase C: per-neighbor M conv from LDS-staged tile, gated accumulate ----
    f32x4 magg[4];
#pragma unroll
    for (int mt = 0; mt < 4; ++mt) magg[mt] = (f32x4){0.f, 0.f, 0.f, 0.f};
    int pp = ((t >> 4) + 1) * 18 + (t & 15) + 1;   // own pixel, padded coords
    for (int ii = 0; ii < deg; ++ii) {
        // stage current neighbor (regs -> LDS ch0-15); prefetch next
        *(bf16x8*)(sAH + pp * SAH_STRIDE) = nbA0;
        *(bf16x8*)(sAH + pp * SAH_STRIDE + 8) = nbA1;
        if (ii + 1 < deg) {
            const short* mp = (const short*)Xin + (b * 64 + ejl[ii + 1]) * 4096 + t * 16;
            nbB0 = *(const bf16x8*)(mp);
            nbB1 = *(const bf16x8*)(mp + 8);
        }
        __syncthreads();
        float evv = evs[ii];
        f32x4 acc[4];
#pragma unroll
        for (int mt = 0; mt < 4; ++mt) acc[mt] = (f32x4){bm_l, bm_l, bm_l, bm_l};
#pragma unroll
        for (int sp = 0; sp < 5; ++sp) {
            bf16x8 Bf = *(const bf16x8*)(WmS + sp * 512 + lane * 8);
            int s2 = sp * 2 + (quad >> 1);
            if (s2 > 8) s2 = 8;                  // phantom shift: B half is zero
            int ky = s2 / 3, kx = s2 - (s2 / 3) * 3;
            int cib = (quad & 1) * 8;
#pragma unroll
            for (int mt = 0; mt < 4; ++mt) {
                int pc = (wv * 4 + mt + ky) * 18 + n16 + kx;
                bf16x8 A = *(const bf16x8*)(sAH + pc * SAH_STRIDE + cib);
                acc[mt] = __builtin_amdgcn_mfma_f32_16x16x32_bf16(A, Bf, acc[mt], 0, 0, 0);
            }
        }
#pragma unroll
        for (int mt = 0; mt < 4; ++mt)
#pragma unroll
            for (int r = 0; r < 4; ++r)
                magg[mt][r] += sigm(evv * T_lane[mt * 4 + r] + gb_l) * acc[mt][r];
        nbA0 = nbB0; nbA1 = nbB1;
        __syncthreads();   // conv reads done before next stage overwrites
    }
    // ---- phase D: M_agg -> ch0-15 interior (C-layout: every slot exactly once) ----
#pragma unroll
    for (int mt = 0; mt < 4; ++mt)
#pragma unroll
        for (int r = 0; r < 4; ++r) {
            int p = (wv * 4 + mt + 1) * 18 + quad * 4 + r + 1;
            sAH[p * SAH_STRIDE + n16] = f2bs(magg[mt][r]);
        }
    __syncthreads();

    // ---- zr conv: 9 shifts x 2 ntiles x 4 Mtiles ----
    float bz = Wf[21025 + n16], br = Wf[21025 + 16 + n16];
    f32x4 accZ[4], accR[4];
#pragma unroll
    for (int mt = 0; mt < 4; ++mt) {
        accZ[mt] = (f32x4){bz, bz, bz, bz};
        accR[mt] = (f32x4){br, br, br, br};
    }
#pragma unroll
    for (int s = 0; s < 9; ++s) {
        int ky = s / 3, kx = s - (s / 3) * 3;
        bf16x8 B0 = *(const bf16x8*)(WgS + (s * 2 + 0) * 512 + lane * 8);
        bf16x8 B1 = *(const bf16x8*)(WgS + (s * 2 + 1) * 512 + lane * 8);
#pragma unroll
        for (int mt = 0; mt < 4; ++mt) {
            int pc = (wv * 4 + mt + ky) * 18 + n16 + kx;
            bf16x8 A = *(const bf16x8*)(sAH + pc * SAH_STRIDE + quad * 8);
            accZ[mt] = __builtin_amdgcn_mfma_f32_16x16x32_bf16(A, B0, accZ[mt], 0, 0, 0);
            accR[mt] = __builtin_amdgcn_mfma_f32_16x16x32_bf16(A, B1, accR[mt], 0, 0, 0);
        }
    }
    // ---- z, r, h, r*h ----
    float zf[16], hf[16], rh[16];
#pragma unroll
    for (int mt = 0; mt < 4; ++mt)
#pragma unroll
        for (int r = 0; r < 4; ++r) {
            int k = mt * 4 + r;
            int ps = (wv * 4 + mt + 1) * 18 + quad * 4 + r + 1;
            hf[k] = bs2f(sAH[ps * SAH_STRIDE + 16 + n16]);
            zf[k] = sigm(accZ[mt][r]);
            rh[k] = sigm(accR[mt][r]) * hf[k];
        }
    __syncthreads();
#pragma unroll
    for (int mt = 0; mt < 4; ++mt)
#pragma unroll
        for (int r = 0; r < 4; ++r) {
            int ps = (wv * 4 + mt + 1) * 18 + quad * 4 + r + 1;
            sAH[ps * SAH_STRIDE + 16 + n16] = f2bs(rh[mt * 4 + r]);
        }
    __syncthreads();

    // ---- cand conv ----
    float bcl = Wf[25665 + n16];
    f32x4 accC[4];
#pragma unroll
    for (int mt = 0; mt < 4; ++mt) accC[mt] = (f32x4){bcl, bcl, bcl, bcl};
#pragma unroll
    for (int s = 0; s < 9; ++s) {
        int ky = s / 3, kx = s - (s / 3) * 3;
        bf16x8 Bc = *(const bf16x8*)(WcS + s * 512 + lane * 8);
#pragma unroll
        for (int mt = 0; mt < 4; ++mt) {
            int pc = (wv * 4 + mt + ky) * 18 + n16 + kx;
            bf16x8 A = *(const bf16x8*)(sAH + pc * SAH_STRIDE + quad * 8);
            accC[mt] = __builtin_amdgcn_mfma_f32_16x16x32_bf16(A, Bc, accC[mt], 0, 0, 0);
        }
    }
    // ---- epilogue: X = (1-z)h + z*tanh(cand); write Xout; q/k of new X ----
    __shared__ float xred[64];
    float ssum = 0.f;
    short* xo = (short*)Xout + bn * 4096;
#pragma unroll
    for (int mt = 0; mt < 4; ++mt)
#pragma unroll
        for (int r = 0; r < 4; ++r) {
            int k = mt * 4 + r;
            float cand = tanh_fast(accC[mt][r]);
            float nx = (1.f - zf[k]) * hf[k] + zf[k] * cand;
            ssum += nx;
            int pix = (wv * 4 + mt) * 16 + quad * 4 + r;
            xo[pix * 16 + n16] = f2bs(nx);
        }
    ssum += __shfl_xor(ssum, 16, 64);
    ssum += __shfl_xor(ssum, 32, 64);
    if (lane < 16) xred[wv * 16 + lane] = ssum;
    __syncthreads();
    if (t < 64) {
        int d = t & 31;
        const float* W = (t < 32) ? Wf : Wf + 544;
        float a = (t < 32) ? Wf[512 + d] : Wf[1056 + d];
#pragma unroll
        for (int c = 0; c < 16; ++c) {
            float xc = (xred[c] + xred[16 + c] + xred[32 + c] + xred[48 + c]) * (1.f / 256.f);
            a += xc * W[c * 32 + d];
        }
        if (t < 32) qout[bn * 32 + d] = a; else kout[bn * 32 + d] = a;
    }
}

extern "C" void kernel_launch(void* const* d_in, const int* in_sizes, int n_in,
                              void* d_out, int out_size, void* d_ws, size_t ws_size,
                              hipStream_t stream)
{
    const void* seed = d_in[0];
    const int* edge = (const int*)d_in[1];
    int E = in_sizes[1] / 2;  // 224

    float* ws = (float*)d_ws;
    short* Xb0 = (short*)ws;                         // 4,194,304 shorts (8 MB)
    short* Xb1 = (short*)d_out;                      // scratch X; pack overwrites at end
    float* qv0 = ws + 2097152;                       // 32768
    float* kv0 = qv0 + 32768;
    float* qv1 = kv0 + 32768;
    float* kv1 = qv1 + 32768;
    float* Tswz = kv1 + 32768;                       // 4096
    float* Wf = Tswz + 4096;                         // 25681
    int* flag = (int*)(Wf + WF_TOTAL);
    int* counts = flag + 16;
    int* lists = counts + 64;                        // 512
    __hip_bfloat16* swz = (__hip_bfloat16*)(ws + 2260000);  // 16B-aligned, 16384 bf16

    const short* WgS = (const short*)swz;
    const short* WcS = (const short*)(swz + 9216);
    const short* WmS = (const short*)(swz + 13824);

    setup_kernel<<<Bt * Nt, 256, 0, stream>>>(
        seed,
        d_in[2], d_in[3], d_in[4], d_in[5], d_in[6], d_in[7], d_in[8], d_in[9],
        d_in[10], d_in[11], d_in[12], d_in[13], d_in[14], d_in[15], d_in[16],
        d_in[17], d_in[18], d_in[19],
        edge, E, Wf, Tswz, counts, lists, swz, Xb0, qv0, kv0, flag);

    short* Xs[2] = {Xb0, Xb1};
    float* qs[2] = {qv0, qv1};
    float* ks[2] = {kv0, kv1};
    for (int it = 0; it < KITERt; ++it) {
        int in = it & 1, on = in ^ 1;
        iter_kernel<<<Bt * Nt, 256, 0, stream>>>(
            (const __hip_bfloat16*)Xs[in], (__hip_bfloat16*)Xs[on],
            qs[in], ks[in], qs[on], ks[on],
            Tswz, WmS, WgS, WcS, Wf, edge, counts, lists, E);
    }

    // KITERt even -> final X parity is buffer 0 (ws); pack writes d_out last
    pack_kernel<<<out_size / 256, 256, 0, stream>>>(Xs[KITERt & 1], d_out, flag);
}